// Round 1
// baseline (519.185 us; speedup 1.0000x reference)
//
#include <hip/hip_runtime.h>
#include <stdint.h>
#include <stddef.h>

// SinkhornScorer fused kernel for MI355X (gfx950).
// One workgroup (256 threads) per batch element b:
//   phase 1: stream x_b,y_b (36x768 fp32) once: fp32 row stats + bf16 LDS tiles
//   phase 2: MFMA 16x16x32 bf16 -> raw dot products, scaled by 1/(|x||y|)
//   phase 3: wave-0 Sinkhorn (20 iters) in base-2 log domain
//   phase 4: Z write + <P,S> block reduction

typedef float  f4  __attribute__((ext_vector_type(4)));
typedef short  s8v __attribute__((ext_vector_type(8)));
typedef unsigned int u2v __attribute__((ext_vector_type(2)));

#define HD   768
#define MR   36          // rows (M == N == 36)
#define KC   128         // K-chunk
#define NCH  6           // 768/128
#define AS   136         // LDS row stride (bf16 elems) for A/B tiles: odd*8 -> 2-way conflicts max
#define CS   44          // LDS row stride (floats) for C2/C2T: (11i+jj)%8 spreads banks
#define LOG2E 1.4426950408889634f
#define LN2   0.6931471805599453f
#define L272  6.169925001442312f   // log2(72) = -norm_c in base-2
#define KC2   (10.0f*LOG2E)        // couplings scale: /REG then *log2e
#define NEGB  (-1.0e30f)

__device__ __forceinline__ uint32_t pkbf2(float a, float b) {
    // two fp32 -> packed bf16 (RNE)
    uint32_t ua = __float_as_uint(a), ub = __float_as_uint(b);
    ua += 0x7FFFu + ((ua >> 16) & 1u);
    ub += 0x7FFFu + ((ub >> 16) & 1u);
    return (ua >> 16) | (ub & 0xFFFF0000u);
}

__global__ __launch_bounds__(256, 3) void sinkhorn_kernel(
    const float* __restrict__ X, const float* __restrict__ Y,
    const float* __restrict__ LG, const float* __restrict__ LB,
    const float* __restrict__ W,  const float* __restrict__ BL,
    float* __restrict__ OUT, int NB)
{
    __shared__ __align__(16) uint16_t Al[48 * AS];   // x bf16 tile (rows 36..47 unused garbage -> discarded outputs)
    __shared__ __align__(16) uint16_t Bt[48 * AS];   // y bf16 tile
    __shared__ __align__(16) float C2 [37 * CS];     // couplings * log2e, cols 37..39 = -1e30 pad
    __shared__ __align__(16) float C2T[37 * CS];     // transpose
    __shared__ __align__(16) float u_l[40];
    __shared__ __align__(16) float v_l[40];
    __shared__ float stx[MR * 3], sty[MR * 3];       // per-row {Sx, Sxx, Sxw}
    __shared__ float rnx[MR], rny[MR];               // 1/||row||
    __shared__ float s_gw, s_bw, red[4];

    const int t  = threadIdx.x;
    const int b  = blockIdx.x;
    const int wv = t >> 6, ln = t & 63;
    const int c4 = t & 31, gg = t >> 5;

    // ---- one-time inits (no barrier needed before first chunk barrier) ----
    if (t < 40) { u_l[t] = 0.0f; v_l[t] = 0.0f; }
    if (t < 37) {
        C2 [t * CS + 37] = NEGB; C2 [t * CS + 38] = NEGB; C2 [t * CS + 39] = NEGB;
        C2T[t * CS + 37] = NEGB; C2T[t * CS + 38] = NEGB; C2T[t * CS + 39] = NEGB;
    }
    if (wv == 3) {  // Sgw = sum g*w, Sbw = sum b*w (wave 3, once)
        float a = 0.0f, c = 0.0f;
        for (int q = 0; q < 12; ++q) {
            int h = ln + 64 * q;
            float wval = W[h];
            a += LG[h] * wval; c += LB[h] * wval;
        }
        for (int o = 32; o > 0; o >>= 1) { a += __shfl_down(a, o); c += __shfl_down(c, o); }
        if (ln == 0) { s_gw = a; s_bw = c; }
    }

    float sx[5][3], sy[5][3];
    #pragma unroll
    for (int p = 0; p < 5; ++p)
        #pragma unroll
        for (int s = 0; s < 3; ++s) { sx[p][s] = 0.0f; sy[p][s] = 0.0f; }

    f4 acc[3];
    #pragma unroll
    for (int i = 0; i < 3; ++i) acc[i] = (f4){0.0f, 0.0f, 0.0f, 0.0f};

    const float* xb = X + (size_t)b * (MR * HD);
    const float* yb = Y + (size_t)b * (MR * HD);

    const int frow = ln & 15, fq = ln >> 4;          // MFMA fragment row / k-quad
    const int rA = (wv * 16 + frow) * AS + fq * 8;   // A frag base (only waves 0..2 use)

    // ---- phase 1+2: staged K-loop ----
    for (int kc = 0; kc < NCH; ++kc) {
        const int k0 = kc * KC;
        f4 gv = *(const f4*)(LG + k0 + c4 * 4);
        f4 wvec = *(const f4*)(W + k0 + c4 * 4);
        f4 gw = gv * wvec;
        #pragma unroll
        for (int p = 0; p < 5; ++p) {
            if (p < 4 || t < 128) {
                const int row = (p < 4) ? (p * 8 + gg) : (32 + gg);
                f4 xv = *(const f4*)(xb + row * HD + k0 + c4 * 4);
                sx[p][0] += (xv.x + xv.y) + (xv.z + xv.w);
                sx[p][1] += xv.x * xv.x + xv.y * xv.y + xv.z * xv.z + xv.w * xv.w;
                sx[p][2] += xv.x * gw.x + xv.y * gw.y + xv.z * gw.z + xv.w * gw.w;
                u2v px; px.x = pkbf2(xv.x, xv.y); px.y = pkbf2(xv.z, xv.w);
                *(u2v*)&Al[row * AS + c4 * 4] = px;
                f4 yv = *(const f4*)(yb + row * HD + k0 + c4 * 4);
                sy[p][0] += (yv.x + yv.y) + (yv.z + yv.w);
                sy[p][1] += yv.x * yv.x + yv.y * yv.y + yv.z * yv.z + yv.w * yv.w;
                sy[p][2] += yv.x * gw.x + yv.y * gw.y + yv.z * gw.z + yv.w * gw.w;
                u2v py; py.x = pkbf2(yv.x, yv.y); py.y = pkbf2(yv.z, yv.w);
                *(u2v*)&Bt[row * AS + c4 * 4] = py;
            }
        }
        __syncthreads();
        if (wv < 3) {
            #pragma unroll
            for (int ks = 0; ks < 4; ++ks) {
                s8v af = *(const s8v*)&Al[rA + ks * 32];
                #pragma unroll
                for (int tn = 0; tn < 3; ++tn) {
                    s8v bf = *(const s8v*)&Bt[(tn * 16 + frow) * AS + fq * 8 + ks * 32];
                    acc[tn] = __builtin_amdgcn_mfma_f32_16x16x32_bf16(af, bf, acc[tn], 0, 0, 0);
                }
            }
        }
        __syncthreads();
    }

    // ---- stats reduction: 32-lane groups own fixed rows ----
    #pragma unroll
    for (int p = 0; p < 5; ++p) {
        const int row = (p < 4) ? (p * 8 + gg) : (32 + gg);
        #pragma unroll
        for (int s = 0; s < 3; ++s) {
            float a = sx[p][s], c = sy[p][s];
            for (int o = 16; o > 0; o >>= 1) { a += __shfl_down(a, o, 32); c += __shfl_down(c, o, 32); }
            if ((t & 31) == 0 && row < MR) { stx[row * 3 + s] = a; sty[row * 3 + s] = c; }
        }
    }
    __syncthreads();

    // ---- derived per-row: 1/norm, dustbin scores (LayerNorm -> linear -> tanh) ----
    {
        const float blin = BL[0];
        if (t < MR) {
            float Sx = stx[t * 3], Sxx = stx[t * 3 + 1], Sxw = stx[t * 3 + 2];
            rnx[t] = __builtin_amdgcn_rsqf(Sxx);
            float mu  = Sx * (1.0f / HD);
            float var = Sxx * (1.0f / HD) - mu * mu;
            float rsd = __builtin_amdgcn_rsqf(var + 1e-5f);
            float lin = (Sxw - mu * s_gw) * rsd + s_bw + blin;
            float e   = __builtin_amdgcn_exp2f(2.0f * LOG2E * lin);
            float th  = (e - 1.0f) / (e + 1.0f);
            C2 [t * CS + 36] = th * KC2;
            C2T[36 * CS + t] = th * KC2;
        } else if (t >= 64 && t < 64 + MR) {
            int j = t - 64;
            float Sy = sty[j * 3], Syy = sty[j * 3 + 1], Syw = sty[j * 3 + 2];
            rny[j] = __builtin_amdgcn_rsqf(Syy);
            float mu  = Sy * (1.0f / HD);
            float var = Syy * (1.0f / HD) - mu * mu;
            float rsd = __builtin_amdgcn_rsqf(var + 1e-5f);
            float lin = (Syw - mu * s_gw) * rsd + s_bw + blin;
            float e   = __builtin_amdgcn_exp2f(2.0f * LOG2E * lin);
            float th  = (e - 1.0f) / (e + 1.0f);
            C2 [36 * CS + j] = th * KC2;
            C2T[j * CS + 36] = th * KC2;
        } else if (t == 128) {
            C2 [36 * CS + 36] = -100.0f * KC2;   // ALPHA_BOTH/REG in base-2
            C2T[36 * CS + 36] = -100.0f * KC2;
        }
    }
    __syncthreads();

    // ---- scores -> couplings (base-2) into C2 and C2T ----
    if (wv < 3) {
        #pragma unroll
        for (int tn = 0; tn < 3; ++tn) {
            #pragma unroll
            for (int r = 0; r < 4; ++r) {
                int i = wv * 16 + fq * 4 + r;   // A-operand index (x row)
                int j = tn * 16 + frow;         // B-operand index (y row)
                if (i < MR && j < MR) {
                    float v = acc[tn][r] * rnx[i] * rny[j] * KC2;
                    C2 [i * CS + j] = v;
                    C2T[j * CS + i] = v;
                }
            }
        }
    }
    __syncthreads();

    // ---- Sinkhorn: wave 0, lane = row/col index, base-2 log domain ----
    if (wv == 0 && ln < 37) {
        const int i = ln;
        const float lmu = (i < MR) ? -L272 : -1.0f;  // log2 marginals (mu == nu for M==N)
        f4 cr[10], ct[10];
        #pragma unroll
        for (int jj = 0; jj < 10; ++jj) {
            cr[jj] = *(const f4*)(&C2 [i * CS + jj * 4]);
            ct[jj] = *(const f4*)(&C2T[i * CS + jj * 4]);
        }
        for (int it = 0; it < 20; ++it) {
            // u-update: LSE over columns j of (C + v)
            float tt[40];
            float m = -3.0e38f;
            #pragma unroll
            for (int jj = 0; jj < 10; ++jj) {
                f4 vv = *(const f4*)(&v_l[jj * 4]);
                f4 s = cr[jj] + vv;
                tt[jj*4+0] = s.x; tt[jj*4+1] = s.y; tt[jj*4+2] = s.z; tt[jj*4+3] = s.w;
                m = fmaxf(m, fmaxf(fmaxf(s.x, s.y), fmaxf(s.z, s.w)));
            }
            float ss = 0.0f;
            #pragma unroll
            for (int jj = 0; jj < 10; ++jj)
                ss += __builtin_amdgcn_exp2f(tt[jj*4+0] - m) + __builtin_amdgcn_exp2f(tt[jj*4+1] - m)
                    + __builtin_amdgcn_exp2f(tt[jj*4+2] - m) + __builtin_amdgcn_exp2f(tt[jj*4+3] - m);
            u_l[i] = lmu - (m + __builtin_amdgcn_logf(ss));
            // v-update: LSE over rows i of (C + u) == over cols of C^T
            m = -3.0e38f;
            #pragma unroll
            for (int jj = 0; jj < 10; ++jj) {
                f4 uu = *(const f4*)(&u_l[jj * 4]);
                f4 s = ct[jj] + uu;
                tt[jj*4+0] = s.x; tt[jj*4+1] = s.y; tt[jj*4+2] = s.z; tt[jj*4+3] = s.w;
                m = fmaxf(m, fmaxf(fmaxf(s.x, s.y), fmaxf(s.z, s.w)));
            }
            ss = 0.0f;
            #pragma unroll
            for (int jj = 0; jj < 10; ++jj)
                ss += __builtin_amdgcn_exp2f(tt[jj*4+0] - m) + __builtin_amdgcn_exp2f(tt[jj*4+1] - m)
                    + __builtin_amdgcn_exp2f(tt[jj*4+2] - m) + __builtin_amdgcn_exp2f(tt[jj*4+3] - m);
            v_l[i] = lmu - (m + __builtin_amdgcn_logf(ss));
        }
    }
    __syncthreads();

    // ---- epilogue: Z write + total = <exp(Z), scores>/TEMP ----
    float tot = 0.0f;
    const size_t ob = (size_t)b * 1369;
    for (int e = t; e < 1369; e += 256) {
        int i = e / 37, j = e - i * 37;
        float c2v = C2[i * CS + j];
        float z2  = c2v + u_l[i] + v_l[j] + L272;   // - norm_c == + log2(72) in base-2
        OUT[ob + e] = z2 * LN2;
        if (i < MR && j < MR)
            tot += __builtin_amdgcn_exp2f(z2) * (c2v * (0.1f * LN2));  // scores = C2 * REG * ln2
    }
    for (int o = 32; o > 0; o >>= 1) tot += __shfl_down(tot, o);
    if (ln == 0) red[wv] = tot;
    __syncthreads();
    if (t == 0) OUT[(size_t)NB * 1369 + b] = (red[0] + red[1] + red[2] + red[3]) * 10.0f;  // /TEMP
}

extern "C" void kernel_launch(void* const* d_in, const int* in_sizes, int n_in,
                              void* d_out, int out_size, void* d_ws, size_t ws_size,
                              hipStream_t stream) {
    const float* X  = (const float*)d_in[0];
    const float* Y  = (const float*)d_in[1];
    const float* LG = (const float*)d_in[2];
    const float* LB = (const float*)d_in[3];
    const float* W  = (const float*)d_in[4];
    const float* BL = (const float*)d_in[5];
    const int NB = in_sizes[0] / (MR * HD);   // 2048
    hipLaunchKernelGGL(sinkhorn_kernel, dim3(NB), dim3(256), 0, stream,
                       X, Y, LG, LB, W, BL, (float*)d_out, NB);
}